// Round 4
// baseline (494.852 us; speedup 1.0000x reference)
//
#include <hip/hip_runtime.h>

#define N_NODES 50000
#define N_EDGES 800000
#define CH 128
#define N_GRAPHS 128
#define N_LAYERS 3
#define OUT_CH 16
#define BN_EPS 1e-5f
#define NCHUNK ((N_NODES + 1023) / 1024)
#define NSPLIT 8
#define BPQ (N_NODES / 16)        // 3125 blocks per quarter-pass (16 nodes/block)
#define QSTRIDE ((size_t)N_NODES * 32)   // halfwords per quarter region

typedef unsigned short ushort_t;
typedef __attribute__((ext_vector_type(8))) short bf16x8;
typedef __attribute__((ext_vector_type(4))) float f32x4;

__device__ inline ushort_t f2b(float f) {
    unsigned u = __float_as_uint(f);
    unsigned r = (u + 0x7fffu + ((u >> 16) & 1u)) >> 16;
    return (ushort_t)r;
}
__device__ inline float b2f(ushort_t b) {
    return __uint_as_float((unsigned)b << 16);
}

// ---------------- fp32 x -> bf16 channel-blocked [4][N][32] ----------------
__global__ __launch_bounds__(256) void cast_kernel(const float4* __restrict__ x,
                                                   ushort_t* __restrict__ xb) {
    int i = blockIdx.x * blockDim.x + threadIdx.x;       // over N*32 float4 groups
    if (i >= N_NODES * 32) return;
    int node = i >> 5, v4 = i & 31;                      // v4: which 4-ch group
    int q = v4 >> 3, co = (v4 & 7) * 4;                  // quarter, offset within quarter
    float4 v = x[i];
    ushort4 o;
    o.x = f2b(v.x); o.y = f2b(v.y); o.z = f2b(v.z); o.w = f2b(v.w);
    *(ushort4*)&xb[(size_t)q * QSTRIDE + (size_t)node * 32 + co] = o;
}

// ---------------- CSR build ----------------
__global__ void hist_kernel(const int* __restrict__ dst, int* __restrict__ deg) {
    int i = blockIdx.x * blockDim.x + threadIdx.x;
    if (i < N_EDGES) atomicAdd(&deg[dst[i]], 1);
}

__global__ __launch_bounds__(1024) void scan1_kernel(const int* __restrict__ deg,
                                                     int* __restrict__ rowptr,
                                                     int* __restrict__ bsum) {
    __shared__ int sdata[1024];
    int t = threadIdx.x, base = blockIdx.x * 1024;
    int v = (base + t < N_NODES) ? deg[base + t] : 0;
    sdata[t] = v;
    __syncthreads();
    #pragma unroll
    for (int off = 1; off < 1024; off <<= 1) {
        int y = (t >= off) ? sdata[t - off] : 0;
        __syncthreads();
        sdata[t] += y;
        __syncthreads();
    }
    if (base + t < N_NODES) rowptr[base + t] = sdata[t] - v;
    if (t == 1023) bsum[blockIdx.x] = sdata[1023];
}

__global__ void scan2_kernel(const int* __restrict__ bsum, int* __restrict__ boff) {
    int lane = threadIdx.x;
    int v = (lane < NCHUNK) ? bsum[lane] : 0;
    int orig = v;
    #pragma unroll
    for (int off = 1; off < 64; off <<= 1) {
        int tv = __shfl_up(v, off);
        if (lane >= off) v += tv;
    }
    if (lane < NCHUNK) boff[lane] = v - orig;
}

__global__ __launch_bounds__(1024) void scan3_kernel(int* __restrict__ rowptr,
                                                     const int* __restrict__ boff,
                                                     int* __restrict__ cursor) {
    int i = blockIdx.x * 1024 + threadIdx.x;
    if (i < N_NODES) {
        int r = rowptr[i] + boff[blockIdx.x];
        rowptr[i] = r;
        cursor[i] = r;
    }
    if (i == 0) rowptr[N_NODES] = N_EDGES;
}

__global__ void fill_kernel(const int* __restrict__ src, const int* __restrict__ dst,
                            int* __restrict__ cursor, int* __restrict__ esrc) {
    int i = blockIdx.x * blockDim.x + threadIdx.x;
    if (i < N_EDGES) {
        int p = atomicAdd(&cursor[dst[i]], 1);
        esrc[p] = src[i];
    }
}

__global__ void starts_kernel(const int* __restrict__ batch, int* __restrict__ starts) {
    int i = blockIdx.x * blockDim.x + threadIdx.x;
    if (i >= N_NODES) return;
    int b = batch[i];
    if (i == 0) {
        for (int g = 0; g <= b; ++g) starts[g] = 0;
    } else {
        int pb = batch[i - 1];
        for (int g = pb + 1; g <= b; ++g) starts[g] = i;
    }
    if (i == N_NODES - 1) {
        for (int g = b + 1; g <= N_GRAPHS; ++g) starts[g] = N_NODES;
    }
}

// ---------------- weight / epilogue prep ----------------
__global__ __launch_bounds__(256) void wprep_kernel(const float* __restrict__ W1,
                                                    const float* __restrict__ W2,
                                                    ushort_t* __restrict__ Wt) {
    int i = blockIdx.x * blockDim.x + threadIdx.x;
    if (i >= 6 * CH * CH) return;
    int mat = i / (CH * CH), rem = i % (CH * CH);
    int n = rem / CH, k = rem % CH;
    const float* Wsrc = (mat < 3) ? (W1 + (size_t)mat * CH * CH)
                                  : (W2 + (size_t)(mat - 3) * CH * CH);
    Wt[i] = f2b(Wsrc[k * CH + n]);
}

__global__ void eprep_kernel(const float* __restrict__ b1, const float* __restrict__ b2,
                             const float* __restrict__ gamma, const float* __restrict__ beta,
                             const float* __restrict__ mean, const float* __restrict__ var,
                             float* __restrict__ scale, float* __restrict__ shift) {
    int i = blockIdx.x * blockDim.x + threadIdx.x;
    if (i >= 6 * CH) return;
    int mat = i / CH, c = i % CH;
    if (mat < 3) {
        scale[i] = 1.f;
        shift[i] = b1[mat * CH + c];
    } else {
        int l = mat - 3;
        float inv = gamma[l * CH + c] * rsqrtf(var[l * CH + c] + BN_EPS);
        scale[i] = inv;
        shift[i] = (b2[l * CH + c] - mean[l * CH + c]) * inv + beta[l * CH + c];
    }
}

// ---------------- aggregation, quarter-pass (L2-resident working set) ----------------
// grid = 4*BPQ blocks; q = bid/BPQ (temporal separation by dispatch order).
// block = 256 thr = 16 groups of 16 lanes; group handles one node's 32-ch quarter.
__global__ __launch_bounds__(256) void aggq_kernel(const unsigned* __restrict__ h,
                                                   const int* __restrict__ rowptr,
                                                   const int* __restrict__ esrc,
                                                   unsigned* __restrict__ z) {
    int bid = blockIdx.x;
    int q = bid / BPQ, bb = bid % BPQ;
    int t = threadIdx.x;
    int g = t >> 4, lane16 = t & 15;
    int node = bb * 16 + g;                    // N = 3125*16 exactly
    const unsigned* hq = h + (size_t)q * (QSTRIDE / 2);   // dword view: 16 dwords/node
    unsigned self = hq[(size_t)node * 16 + lane16];
    float ax = __uint_as_float(self << 16);
    float ay = __uint_as_float(self & 0xffff0000u);
    int beg = rowptr[node], end = rowptr[node + 1];
    int e = beg;
    for (; e + 2 <= end; e += 2) {
        int s0 = esrc[e], s1 = esrc[e + 1];
        unsigned u0 = hq[(size_t)s0 * 16 + lane16];
        unsigned u1 = hq[(size_t)s1 * 16 + lane16];
        ax += __uint_as_float(u0 << 16) + __uint_as_float(u1 << 16);
        ay += __uint_as_float(u0 & 0xffff0000u) + __uint_as_float(u1 & 0xffff0000u);
    }
    if (e < end) {
        unsigned u = hq[(size_t)esrc[e] * 16 + lane16];
        ax += __uint_as_float(u << 16);
        ay += __uint_as_float(u & 0xffff0000u);
    }
    unsigned* zq = z + (size_t)q * (QSTRIDE / 2);
    zq[(size_t)node * 16 + lane16] = ((unsigned)f2b(ay) << 16) | (unsigned)f2b(ax);
}

// ---------------- fused MLP: Out = relu(scale2*(relu(A@W1 + b1))@W2 + shift2) ----------------
// A, Out channel-blocked bf16 [4][N][32]. Wt1/Wt2: [n][k] bf16 (transposed weights).
// Block 256 = 4 waves; wave handles 16 rows; C->A relayout via wave-private LDS (no barrier).
__global__ __launch_bounds__(256) void mlp_kernel(const ushort_t* __restrict__ A,
                                                  const ushort_t* __restrict__ Wt1,
                                                  const ushort_t* __restrict__ Wt2,
                                                  const float* __restrict__ shift1,
                                                  const float* __restrict__ scale2,
                                                  const float* __restrict__ shift2,
                                                  ushort_t* __restrict__ Out) {
    __shared__ ushort_t sA[4][16][136];   // [wave][row][col], padded stride
    int t = threadIdx.x;
    int wave = t >> 6, lane = t & 63;
    int quad = lane >> 4, l16 = lane & 15;
    int row0 = blockIdx.x * 64 + wave * 16;
    if (row0 >= N_NODES) return;          // no block-wide syncs -> safe early exit
    int arow = row0 + l16;
    if (arow > N_NODES - 1) arow = N_NODES - 1;

    // A fragments from blocked layout: quarter ks holds k in [ks*32, ks*32+32)
    bf16x8 afrag[4];
    #pragma unroll
    for (int ks = 0; ks < 4; ++ks)
        afrag[ks] = *(const bf16x8*)(A + (size_t)ks * QSTRIDE + (size_t)arow * 32 + quad * 8);

    // ---- GEMM1 ----
    f32x4 acc[8];
    #pragma unroll
    for (int ct = 0; ct < 8; ++ct) acc[ct] = (f32x4){0.f, 0.f, 0.f, 0.f};
    #pragma unroll
    for (int ct = 0; ct < 8; ++ct) {
        const ushort_t* bbase = Wt1 + (size_t)(ct * 16 + l16) * CH + quad * 8;
        #pragma unroll
        for (int ks = 0; ks < 4; ++ks) {
            bf16x8 bfrag = *(const bf16x8*)(bbase + ks * 32);
            acc[ct] = __builtin_amdgcn_mfma_f32_16x16x32_bf16(afrag[ks], bfrag, acc[ct], 0, 0, 0);
        }
    }
    // relu + bias -> LDS strip (C-layout: row=quad*4+r, col=ct*16+l16)
    #pragma unroll
    for (int ct = 0; ct < 8; ++ct) {
        int col = ct * 16 + l16;
        float sh = shift1[col];
        #pragma unroll
        for (int r = 0; r < 4; ++r)
            sA[wave][quad * 4 + r][col] = f2b(fmaxf(acc[ct][r] + sh, 0.f));
    }

    // ---- GEMM2 ---- (A2 frags from LDS; same-wave lgkmcnt ordering, no barrier)
    bf16x8 afrag2[4];
    #pragma unroll
    for (int ks = 0; ks < 4; ++ks)
        afrag2[ks] = *(const bf16x8*)&sA[wave][l16][ks * 32 + quad * 8];

    f32x4 acc2[8];
    #pragma unroll
    for (int ct = 0; ct < 8; ++ct) acc2[ct] = (f32x4){0.f, 0.f, 0.f, 0.f};
    #pragma unroll
    for (int ct = 0; ct < 8; ++ct) {
        const ushort_t* bbase = Wt2 + (size_t)(ct * 16 + l16) * CH + quad * 8;
        #pragma unroll
        for (int ks = 0; ks < 4; ++ks) {
            bf16x8 bfrag = *(const bf16x8*)(bbase + ks * 32);
            acc2[ct] = __builtin_amdgcn_mfma_f32_16x16x32_bf16(afrag2[ks], bfrag, acc2[ct], 0, 0, 0);
        }
    }
    // epilogue -> blocked Out
    #pragma unroll
    for (int ct = 0; ct < 8; ++ct) {
        int col = ct * 16 + l16;
        float sc = scale2[col], sh = shift2[col];
        int qc = col >> 5, co = col & 31;
        #pragma unroll
        for (int r = 0; r < 4; ++r) {
            int row = row0 + quad * 4 + r;
            if (row < N_NODES)
                Out[(size_t)qc * QSTRIDE + (size_t)row * 32 + co] =
                    f2b(fmaxf(acc2[ct][r] * sc + sh, 0.f));
        }
    }
}

// ---------------- pooling (blocked bf16 in) + classifier ----------------
__global__ __launch_bounds__(128) void pool_kernel(const ushort_t* __restrict__ h,
                                                   const int* __restrict__ starts,
                                                   float* __restrict__ pooled) {
    int g = blockIdx.x / NSPLIT, s = blockIdx.x % NSPLIT;
    int c = threadIdx.x;
    int q = c >> 5, co = c & 31;
    const ushort_t* hq = h + (size_t)q * QSTRIDE;
    int beg = starts[g], end = starts[g + 1];
    float sum = 0.f;
    for (int n = beg + s; n < end; n += NSPLIT)
        sum += b2f(hq[(size_t)n * 32 + co]);
    atomicAdd(&pooled[g * CH + c], sum);
}

__global__ __launch_bounds__(256) void cls_kernel(const float* __restrict__ pooled,
                                                  const float* __restrict__ Wc,
                                                  const float* __restrict__ bc,
                                                  float* __restrict__ out) {
    int i = blockIdx.x * blockDim.x + threadIdx.x;
    if (i >= N_GRAPHS * OUT_CH) return;
    int g = i / OUT_CH, o = i % OUT_CH;
    float s = bc[o];
    for (int k = 0; k < CH; ++k) s += pooled[g * CH + k] * Wc[k * OUT_CH + o];
    out[i] = s;
}

// ---------------- launch ----------------
extern "C" void kernel_launch(void* const* d_in, const int* in_sizes, int n_in,
                              void* d_out, int out_size, void* d_ws, size_t ws_size,
                              hipStream_t stream) {
    const float* x     = (const float*)d_in[0];
    const int*   eidx  = (const int*)d_in[1];
    const int*   batch = (const int*)d_in[2];
    const float* W1    = (const float*)d_in[3];
    const float* b1    = (const float*)d_in[4];
    const float* W2    = (const float*)d_in[5];
    const float* b2    = (const float*)d_in[6];
    const float* gamma = (const float*)d_in[7];
    const float* beta  = (const float*)d_in[8];
    const float* mean  = (const float*)d_in[9];
    const float* var   = (const float*)d_in[10];
    const float* Wc    = (const float*)d_in[11];
    const float* bc    = (const float*)d_in[12];
    float* out = (float*)d_out;

    const int* src = eidx;
    const int* dst = eidx + N_EDGES;

    char* w = (char*)d_ws;
    size_t off = 0;
    auto alloc = [&](size_t bytes) { void* p = w + off; off += (bytes + 255) & ~(size_t)255; return p; };
    int*      deg    = (int*)alloc(N_NODES * 4);
    int*      rowptr = (int*)alloc((N_NODES + 1) * 4);
    int*      cursor = (int*)alloc(N_NODES * 4);
    int*      esrc   = (int*)alloc(N_EDGES * 4);
    int*      bsum   = (int*)alloc(NCHUNK * 4);
    int*      boff   = (int*)alloc(NCHUNK * 4);
    int*      starts = (int*)alloc((N_GRAPHS + 1) * 4);
    ushort_t* Bh     = (ushort_t*)alloc((size_t)N_NODES * CH * 2);   // h (blocked)
    ushort_t* Bz     = (ushort_t*)alloc((size_t)N_NODES * CH * 2);   // z (blocked)
    ushort_t* Wt     = (ushort_t*)alloc((size_t)6 * CH * CH * 2);
    float*    scale  = (float*)alloc(6 * CH * 4);
    float*    shift  = (float*)alloc(6 * CH * 4);
    float*    pooled = (float*)alloc(N_GRAPHS * CH * 4);
    (void)ws_size; (void)n_in; (void)in_sizes; (void)out_size;

    cast_kernel<<<(N_NODES * 32 + 255) / 256, 256, 0, stream>>>((const float4*)x, Bh);
    hipMemsetAsync(deg, 0, N_NODES * 4, stream);
    hipMemsetAsync(pooled, 0, N_GRAPHS * CH * 4, stream);
    hist_kernel<<<(N_EDGES + 255) / 256, 256, 0, stream>>>(dst, deg);
    scan1_kernel<<<NCHUNK, 1024, 0, stream>>>(deg, rowptr, bsum);
    scan2_kernel<<<1, 64, 0, stream>>>(bsum, boff);
    scan3_kernel<<<NCHUNK, 1024, 0, stream>>>(rowptr, boff, cursor);
    fill_kernel<<<(N_EDGES + 255) / 256, 256, 0, stream>>>(src, dst, cursor, esrc);
    starts_kernel<<<(N_NODES + 255) / 256, 256, 0, stream>>>(batch, starts);
    wprep_kernel<<<(6 * CH * CH + 255) / 256, 256, 0, stream>>>(W1, W2, Wt);
    eprep_kernel<<<(6 * CH + 255) / 256, 256, 0, stream>>>(b1, b2, gamma, beta, mean, var, scale, shift);

    const int mlp_grid = (N_NODES + 63) / 64;

    for (int i = 0; i < N_LAYERS; ++i) {
        aggq_kernel<<<4 * BPQ, 256, 0, stream>>>((const unsigned*)Bh, rowptr, esrc,
                                                 (unsigned*)Bz);
        mlp_kernel<<<mlp_grid, 256, 0, stream>>>(Bz,
                                                 Wt + (size_t)i * CH * CH,
                                                 Wt + (size_t)(3 + i) * CH * CH,
                                                 shift + i * CH,
                                                 scale + (3 + i) * CH,
                                                 shift + (3 + i) * CH,
                                                 Bh);
    }

    pool_kernel<<<N_GRAPHS * NSPLIT, 128, 0, stream>>>(Bh, starts, pooled);
    cls_kernel<<<(N_GRAPHS * OUT_CH + 255) / 256, 256, 0, stream>>>(pooled, Wc, bc, out);
}

// Round 5
// 389.440 us; speedup vs baseline: 1.2707x; 1.2707x over previous
//
#include <hip/hip_runtime.h>

#define N_NODES 50000
#define N_EDGES 800000
#define CH 128
#define N_GRAPHS 128
#define N_LAYERS 3
#define OUT_CH 16
#define BN_EPS 1e-5f
#define NCHUNK ((N_NODES + 1023) / 1024)
#define NSPLIT 8
#define NB 196          // dst>>8 buckets (50000/256 -> 196)
#define BCAP 4608       // bucket capacity (mean 4096, sigma~64, 8-sigma headroom)
#define EPB 4096        // edges per bin block

typedef unsigned short ushort_t;
typedef __attribute__((ext_vector_type(8))) short bf16x8;
typedef __attribute__((ext_vector_type(4))) float f32x4;

__device__ inline ushort_t f2b(float f) {
    unsigned u = __float_as_uint(f);
    unsigned r = (u + 0x7fffu + ((u >> 16) & 1u)) >> 16;
    return (ushort_t)r;
}
__device__ inline float b2f(ushort_t b) { return __uint_as_float((unsigned)b << 16); }
__device__ inline float blo(unsigned u) { return __uint_as_float(u << 16); }
__device__ inline float bhi(unsigned u) { return __uint_as_float(u & 0xffff0000u); }

// ---------------- fp32 x -> bf16 flat [N][128] ----------------
__global__ __launch_bounds__(256) void cast_kernel(const float4* __restrict__ x,
                                                   ushort4* __restrict__ xb, int n4) {
    int i = blockIdx.x * blockDim.x + threadIdx.x;
    if (i >= n4) return;
    float4 v = x[i];
    ushort4 o;
    o.x = f2b(v.x); o.y = f2b(v.y); o.z = f2b(v.z); o.w = f2b(v.w);
    xb[i] = o;
}

// ---------------- CSR build ----------------
__global__ void hist_kernel(const int* __restrict__ dst, int* __restrict__ deg) {
    int i = blockIdx.x * blockDim.x + threadIdx.x;
    if (i < N_EDGES) atomicAdd(&deg[dst[i]], 1);
}

__global__ __launch_bounds__(1024) void scan1_kernel(const int* __restrict__ deg,
                                                     int* __restrict__ rowptr,
                                                     int* __restrict__ bsum) {
    __shared__ int sdata[1024];
    int t = threadIdx.x, base = blockIdx.x * 1024;
    int v = (base + t < N_NODES) ? deg[base + t] : 0;
    sdata[t] = v;
    __syncthreads();
    #pragma unroll
    for (int off = 1; off < 1024; off <<= 1) {
        int y = (t >= off) ? sdata[t - off] : 0;
        __syncthreads();
        sdata[t] += y;
        __syncthreads();
    }
    if (base + t < N_NODES) rowptr[base + t] = sdata[t] - v;
    if (t == 1023) bsum[blockIdx.x] = sdata[1023];
}

__global__ void scan2_kernel(const int* __restrict__ bsum, int* __restrict__ boff) {
    int lane = threadIdx.x;
    int v = (lane < NCHUNK) ? bsum[lane] : 0;
    int orig = v;
    #pragma unroll
    for (int off = 1; off < 64; off <<= 1) {
        int tv = __shfl_up(v, off);
        if (lane >= off) v += tv;
    }
    if (lane < NCHUNK) boff[lane] = v - orig;
}

__global__ __launch_bounds__(1024) void scan3_kernel(int* __restrict__ rowptr,
                                                     const int* __restrict__ boff) {
    int i = blockIdx.x * 1024 + threadIdx.x;
    if (i < N_NODES) rowptr[i] += boff[blockIdx.x];
    if (i == 0) rowptr[N_NODES] = N_EDGES;
}

// phase 1: bin edges by dst>>8 with LDS staging -> semi-coalesced bucket appends
__global__ __launch_bounds__(256) void bin_kernel(const int* __restrict__ src,
                                                  const int* __restrict__ dst,
                                                  int* __restrict__ gcur,
                                                  int2* __restrict__ gbuck) {
    __shared__ int lcnt[256];
    __shared__ int lpref[256];
    __shared__ int lpos[NB];
    __shared__ int lbase[NB];
    __shared__ int2 stage[EPB];
    int t = threadIdx.x;
    int e0 = blockIdx.x * EPB;
    int nloc = N_EDGES - e0; if (nloc > EPB) nloc = EPB;

    lcnt[t] = 0;
    __syncthreads();

    int2 ed[16];
    #pragma unroll
    for (int j = 0; j < 16; ++j) {
        int i = j * 256 + t;
        if (i < nloc) {
            ed[j].x = src[e0 + i];
            ed[j].y = dst[e0 + i];
            atomicAdd(&lcnt[ed[j].y >> 8], 1);
        } else ed[j].y = -1;
    }
    __syncthreads();
    int v = lcnt[t];
    lpref[t] = v;
    __syncthreads();
    for (int off = 1; off < 256; off <<= 1) {
        int y = (t >= off) ? lpref[t - off] : 0;
        __syncthreads();
        lpref[t] += y;
        __syncthreads();
    }
    int excl = lpref[t] - v;
    __syncthreads();
    lpref[t] = excl;
    if (t < NB) {
        lpos[t] = excl;
        lbase[t] = atomicAdd(&gcur[t], v);
    }
    __syncthreads();
    #pragma unroll
    for (int j = 0; j < 16; ++j) {
        if (ed[j].y >= 0) {
            int slot = atomicAdd(&lpos[ed[j].y >> 8], 1);
            stage[slot] = ed[j];
        }
    }
    __syncthreads();
    for (int i = t; i < nloc; i += 256) {
        int2 e = stage[i];
        int b = e.y >> 8;
        gbuck[(size_t)b * BCAP + lbase[b] + (i - lpref[b])] = e;
    }
}

// phase 2: per-bucket LDS sort to exact CSR slots, fully coalesced esrc writes
__global__ __launch_bounds__(256) void place_kernel(const int* __restrict__ gcur,
                                                    const int2* __restrict__ gbuck,
                                                    const int* __restrict__ rowptr,
                                                    int* __restrict__ esrc) {
    __shared__ int ssrc[BCAP];
    __shared__ unsigned char sd[BCAP];
    __shared__ int outS[BCAP];
    __shared__ int cnt[256], pref[256], cur[256];
    int b = blockIdx.x, t = threadIdx.x;
    int nb = gcur[b];
    cnt[t] = 0;
    __syncthreads();
    for (int i = t; i < nb; i += 256) {
        int2 e = gbuck[(size_t)b * BCAP + i];
        ssrc[i] = e.x;
        int dl = e.y & 255;
        sd[i] = (unsigned char)dl;
        atomicAdd(&cnt[dl], 1);
    }
    __syncthreads();
    int v = cnt[t];
    pref[t] = v;
    __syncthreads();
    for (int off = 1; off < 256; off <<= 1) {
        int y = (t >= off) ? pref[t - off] : 0;
        __syncthreads();
        pref[t] += y;
        __syncthreads();
    }
    int excl = pref[t] - v;
    __syncthreads();
    pref[t] = excl;
    cur[t] = 0;
    __syncthreads();
    for (int i = t; i < nb; i += 256) {
        int dl = sd[i];
        int p = pref[dl] + atomicAdd(&cur[dl], 1);
        outS[p] = ssrc[i];
    }
    __syncthreads();
    int base = rowptr[b << 8];
    for (int i = t; i < nb; i += 256)
        esrc[base + i] = outS[i];
}

__global__ void starts_kernel(const int* __restrict__ batch, int* __restrict__ starts) {
    int i = blockIdx.x * blockDim.x + threadIdx.x;
    if (i >= N_NODES) return;
    int b = batch[i];
    if (i == 0) {
        for (int g = 0; g <= b; ++g) starts[g] = 0;
    } else {
        int pb = batch[i - 1];
        for (int g = pb + 1; g <= b; ++g) starts[g] = i;
    }
    if (i == N_NODES - 1) {
        for (int g = b + 1; g <= N_GRAPHS; ++g) starts[g] = N_NODES;
    }
}

// ---------------- weight / epilogue prep ----------------
__global__ __launch_bounds__(256) void wprep_kernel(const float* __restrict__ W1,
                                                    const float* __restrict__ W2,
                                                    ushort_t* __restrict__ Wt) {
    int i = blockIdx.x * blockDim.x + threadIdx.x;
    if (i >= 6 * CH * CH) return;
    int mat = i / (CH * CH), rem = i % (CH * CH);
    int n = rem / CH, k = rem % CH;
    const float* Wsrc = (mat < 3) ? (W1 + (size_t)mat * CH * CH)
                                  : (W2 + (size_t)(mat - 3) * CH * CH);
    Wt[i] = f2b(Wsrc[k * CH + n]);
}

__global__ void eprep_kernel(const float* __restrict__ b1, const float* __restrict__ b2,
                             const float* __restrict__ gamma, const float* __restrict__ beta,
                             const float* __restrict__ mean, const float* __restrict__ var,
                             float* __restrict__ scale, float* __restrict__ shift) {
    int i = blockIdx.x * blockDim.x + threadIdx.x;
    if (i >= 6 * CH) return;
    int mat = i / CH, c = i % CH;
    if (mat < 3) {
        scale[i] = 1.f;
        shift[i] = b1[mat * CH + c];
    } else {
        int l = mat - 3;
        float inv = gamma[l * CH + c] * rsqrtf(var[l * CH + c] + BN_EPS);
        scale[i] = inv;
        shift[i] = (b2[l * CH + c] - mean[l * CH + c]) * inv + beta[l * CH + c];
    }
}

// ---------------- aggregation: flat layout, wave/node, 8-edge unroll ----------------
__global__ __launch_bounds__(256) void agg_kernel(const unsigned* __restrict__ h2,
                                                  const int* __restrict__ rowptr,
                                                  const int* __restrict__ esrc,
                                                  unsigned* __restrict__ z2) {
    int wid = (blockIdx.x * 256 + threadIdx.x) >> 6;
    int lane = threadIdx.x & 63;
    if (wid >= N_NODES) return;
    unsigned self = h2[(size_t)wid * 64 + lane];
    float ax = blo(self), ay = bhi(self);
    int e = rowptr[wid], end = rowptr[wid + 1];
    for (; e + 8 <= end; e += 8) {
        int s0 = esrc[e], s1 = esrc[e+1], s2 = esrc[e+2], s3 = esrc[e+3];
        int s4 = esrc[e+4], s5 = esrc[e+5], s6 = esrc[e+6], s7 = esrc[e+7];
        unsigned u0 = h2[(size_t)s0 * 64 + lane];
        unsigned u1 = h2[(size_t)s1 * 64 + lane];
        unsigned u2 = h2[(size_t)s2 * 64 + lane];
        unsigned u3 = h2[(size_t)s3 * 64 + lane];
        unsigned u4 = h2[(size_t)s4 * 64 + lane];
        unsigned u5 = h2[(size_t)s5 * 64 + lane];
        unsigned u6 = h2[(size_t)s6 * 64 + lane];
        unsigned u7 = h2[(size_t)s7 * 64 + lane];
        ax += blo(u0) + blo(u1) + blo(u2) + blo(u3)
            + blo(u4) + blo(u5) + blo(u6) + blo(u7);
        ay += bhi(u0) + bhi(u1) + bhi(u2) + bhi(u3)
            + bhi(u4) + bhi(u5) + bhi(u6) + bhi(u7);
    }
    for (; e < end; ++e) {
        unsigned u = h2[(size_t)esrc[e] * 64 + lane];
        ax += blo(u); ay += bhi(u);
    }
    z2[(size_t)wid * 64 + lane] = ((unsigned)f2b(ay) << 16) | (unsigned)f2b(ax);
}

// ---------------- fused MLP: Out = relu(scale2*(relu(A@W1 + b1))@W2 + shift2) ----------------
// flat bf16 [N][128]. 256 rows/block, 4 waves x 64 rows; weights staged once in LDS.
__global__ __launch_bounds__(256) void mlp_kernel(const ushort_t* __restrict__ A,
                                                  const ushort_t* __restrict__ Wt1,
                                                  const ushort_t* __restrict__ Wt2,
                                                  const float* __restrict__ shift1,
                                                  const float* __restrict__ scale2,
                                                  const float* __restrict__ shift2,
                                                  ushort_t* __restrict__ Out) {
    __shared__ ushort_t sW[2 * CH * CH];     // 64 KB: Wt1 then Wt2, [n][k]
    __shared__ ushort_t sAx[4][2][16][136];  // 34 KB: per-wave 2 row-tile strips

    int t = threadIdx.x;
    int wave = t >> 6, lane = t & 63;
    int quad = lane >> 4, l16 = lane & 15;

    {   // stage both weight matrices (uint4 = 8 halfwords)
        const uint4* g1 = (const uint4*)Wt1;
        const uint4* g2 = (const uint4*)Wt2;
        uint4* s = (uint4*)sW;
        for (int i = t; i < 2048; i += 256) { s[i] = g1[i]; s[2048 + i] = g2[i]; }
    }
    __syncthreads();

    int rowbase = blockIdx.x * 256 + wave * 64;

    #pragma unroll
    for (int ph = 0; ph < 2; ++ph) {
        int r0 = rowbase + ph * 32;
        // A fragments for 2 row-tiles
        bf16x8 af[2][4];
        #pragma unroll
        for (int rt = 0; rt < 2; ++rt) {
            int arow = r0 + rt * 16 + l16;
            if (arow > N_NODES - 1) arow = N_NODES - 1;
            #pragma unroll
            for (int ks = 0; ks < 4; ++ks)
                af[rt][ks] = *(const bf16x8*)(A + (size_t)arow * CH + ks * 32 + quad * 8);
        }
        // GEMM1
        f32x4 acc[2][8];
        #pragma unroll
        for (int rt = 0; rt < 2; ++rt)
            #pragma unroll
            for (int ct = 0; ct < 8; ++ct) acc[rt][ct] = (f32x4){0.f, 0.f, 0.f, 0.f};
        #pragma unroll
        for (int ct = 0; ct < 8; ++ct)
            #pragma unroll
            for (int ks = 0; ks < 4; ++ks) {
                bf16x8 bf = *(const bf16x8*)&sW[(ct * 16 + l16) * CH + ks * 32 + quad * 8];
                acc[0][ct] = __builtin_amdgcn_mfma_f32_16x16x32_bf16(af[0][ks], bf, acc[0][ct], 0, 0, 0);
                acc[1][ct] = __builtin_amdgcn_mfma_f32_16x16x32_bf16(af[1][ks], bf, acc[1][ct], 0, 0, 0);
            }
        // epilogue1 -> wave-private LDS strips (C layout: row=quad*4+r, col=ct*16+l16)
        #pragma unroll
        for (int rt = 0; rt < 2; ++rt)
            #pragma unroll
            for (int ct = 0; ct < 8; ++ct) {
                int col = ct * 16 + l16;
                float sh = shift1[col];
                #pragma unroll
                for (int r = 0; r < 4; ++r)
                    sAx[wave][rt][quad * 4 + r][col] = f2b(fmaxf(acc[rt][ct][r] + sh, 0.f));
            }
        // GEMM2 (A2 from LDS strips; same-wave ordering, no barrier)
        bf16x8 af2[2][4];
        #pragma unroll
        for (int rt = 0; rt < 2; ++rt)
            #pragma unroll
            for (int ks = 0; ks < 4; ++ks)
                af2[rt][ks] = *(const bf16x8*)&sAx[wave][rt][l16][ks * 32 + quad * 8];
        f32x4 acc2[2][8];
        #pragma unroll
        for (int rt = 0; rt < 2; ++rt)
            #pragma unroll
            for (int ct = 0; ct < 8; ++ct) acc2[rt][ct] = (f32x4){0.f, 0.f, 0.f, 0.f};
        #pragma unroll
        for (int ct = 0; ct < 8; ++ct)
            #pragma unroll
            for (int ks = 0; ks < 4; ++ks) {
                bf16x8 bf = *(const bf16x8*)&sW[CH * CH + (ct * 16 + l16) * CH + ks * 32 + quad * 8];
                acc2[0][ct] = __builtin_amdgcn_mfma_f32_16x16x32_bf16(af2[0][ks], bf, acc2[0][ct], 0, 0, 0);
                acc2[1][ct] = __builtin_amdgcn_mfma_f32_16x16x32_bf16(af2[1][ks], bf, acc2[1][ct], 0, 0, 0);
            }
        // epilogue2 -> global
        #pragma unroll
        for (int rt = 0; rt < 2; ++rt)
            #pragma unroll
            for (int ct = 0; ct < 8; ++ct) {
                int col = ct * 16 + l16;
                float sc = scale2[col], sh = shift2[col];
                #pragma unroll
                for (int r = 0; r < 4; ++r) {
                    int row = r0 + rt * 16 + quad * 4 + r;
                    if (row < N_NODES)
                        Out[(size_t)row * CH + col] = f2b(fmaxf(acc2[rt][ct][r] * sc + sh, 0.f));
                }
            }
    }
}

// ---------------- pooling + classifier ----------------
__global__ __launch_bounds__(128) void pool_kernel(const ushort_t* __restrict__ h,
                                                   const int* __restrict__ starts,
                                                   float* __restrict__ pooled) {
    int g = blockIdx.x / NSPLIT, s = blockIdx.x % NSPLIT;
    int c = threadIdx.x;
    int beg = starts[g], end = starts[g + 1];
    float sum = 0.f;
    for (int n = beg + s; n < end; n += NSPLIT)
        sum += b2f(h[(size_t)n * CH + c]);
    atomicAdd(&pooled[g * CH + c], sum);
}

__global__ __launch_bounds__(256) void cls_kernel(const float* __restrict__ pooled,
                                                  const float* __restrict__ Wc,
                                                  const float* __restrict__ bc,
                                                  float* __restrict__ out) {
    int i = blockIdx.x * blockDim.x + threadIdx.x;
    if (i >= N_GRAPHS * OUT_CH) return;
    int g = i / OUT_CH, o = i % OUT_CH;
    float s = bc[o];
    for (int k = 0; k < CH; ++k) s += pooled[g * CH + k] * Wc[k * OUT_CH + o];
    out[i] = s;
}

// ---------------- launch ----------------
extern "C" void kernel_launch(void* const* d_in, const int* in_sizes, int n_in,
                              void* d_out, int out_size, void* d_ws, size_t ws_size,
                              hipStream_t stream) {
    const float* x     = (const float*)d_in[0];
    const int*   eidx  = (const int*)d_in[1];
    const int*   batch = (const int*)d_in[2];
    const float* W1    = (const float*)d_in[3];
    const float* b1    = (const float*)d_in[4];
    const float* W2    = (const float*)d_in[5];
    const float* b2    = (const float*)d_in[6];
    const float* gamma = (const float*)d_in[7];
    const float* beta  = (const float*)d_in[8];
    const float* mean  = (const float*)d_in[9];
    const float* var   = (const float*)d_in[10];
    const float* Wc    = (const float*)d_in[11];
    const float* bc    = (const float*)d_in[12];
    float* out = (float*)d_out;

    const int* src = eidx;
    const int* dst = eidx + N_EDGES;

    char* w = (char*)d_ws;
    size_t off = 0;
    auto alloc = [&](size_t bytes) { void* p = w + off; off += (bytes + 255) & ~(size_t)255; return p; };
    int*      deg    = (int*)alloc(N_NODES * 4);
    int*      rowptr = (int*)alloc((N_NODES + 1) * 4);
    int*      esrc   = (int*)alloc(N_EDGES * 4);
    int*      bsum   = (int*)alloc(NCHUNK * 4);
    int*      boff   = (int*)alloc(NCHUNK * 4);
    int*      gcur   = (int*)alloc(NB * 4);
    int2*     gbuck  = (int2*)alloc((size_t)NB * BCAP * 8);
    int*      starts = (int*)alloc((N_GRAPHS + 1) * 4);
    ushort_t* Bh     = (ushort_t*)alloc((size_t)N_NODES * CH * 2);
    ushort_t* Bz     = (ushort_t*)alloc((size_t)N_NODES * CH * 2);
    ushort_t* Wt     = (ushort_t*)alloc((size_t)6 * CH * CH * 2);
    float*    scale  = (float*)alloc(6 * CH * 4);
    float*    shift  = (float*)alloc(6 * CH * 4);
    float*    pooled = (float*)alloc(N_GRAPHS * CH * 4);
    (void)ws_size; (void)n_in; (void)in_sizes; (void)out_size;

    const int n4 = (N_NODES * CH) / 4;
    cast_kernel<<<(n4 + 255) / 256, 256, 0, stream>>>((const float4*)x, (ushort4*)Bh, n4);
    hipMemsetAsync(deg, 0, N_NODES * 4, stream);
    hipMemsetAsync(gcur, 0, NB * 4, stream);
    hipMemsetAsync(pooled, 0, N_GRAPHS * CH * 4, stream);
    hist_kernel<<<(N_EDGES + 255) / 256, 256, 0, stream>>>(dst, deg);
    scan1_kernel<<<NCHUNK, 1024, 0, stream>>>(deg, rowptr, bsum);
    scan2_kernel<<<1, 64, 0, stream>>>(bsum, boff);
    scan3_kernel<<<NCHUNK, 1024, 0, stream>>>(rowptr, boff);
    bin_kernel<<<(N_EDGES + EPB - 1) / EPB, 256, 0, stream>>>(src, dst, gcur, gbuck);
    place_kernel<<<NB, 256, 0, stream>>>(gcur, gbuck, rowptr, esrc);
    starts_kernel<<<(N_NODES + 255) / 256, 256, 0, stream>>>(batch, starts);
    wprep_kernel<<<(6 * CH * CH + 255) / 256, 256, 0, stream>>>(W1, W2, Wt);
    eprep_kernel<<<(6 * CH + 255) / 256, 256, 0, stream>>>(b1, b2, gamma, beta, mean, var, scale, shift);

    const int agg_grid = (N_NODES + 3) / 4;
    const int mlp_grid = (N_NODES + 255) / 256;

    for (int i = 0; i < N_LAYERS; ++i) {
        agg_kernel<<<agg_grid, 256, 0, stream>>>((const unsigned*)Bh, rowptr, esrc,
                                                 (unsigned*)Bz);
        mlp_kernel<<<mlp_grid, 256, 0, stream>>>(Bz,
                                                 Wt + (size_t)i * CH * CH,
                                                 Wt + (size_t)(3 + i) * CH * CH,
                                                 shift + i * CH,
                                                 scale + (3 + i) * CH,
                                                 shift + (3 + i) * CH,
                                                 Bh);
    }

    pool_kernel<<<N_GRAPHS * NSPLIT, 128, 0, stream>>>(Bh, starts, pooled);
    cls_kernel<<<(N_GRAPHS * OUT_CH + 255) / 256, 256, 0, stream>>>(pooled, Wc, bc, out);
}